// Round 2
// baseline (61527.045 us; speedup 1.0000x reference)
//
#include <hip/hip_runtime.h>
#include <stdint.h>

// ---------------------------------------------------------------------------
// 2-layer GRU, B=128, T=1024, H=IN=256, OUT=128.
// Dtype (fp32 vs bf16) detected ON DEVICE by probe_init and handled both ways.
//
// 256 blocks x 768 threads, 4 roles x 64 batch-pairs (2 batches/block):
//   role 0 L0X: xt0 = Wx0 . x_t   + bx0   (input known; runs ahead)
//   role 1 L0H: Wh0 . h0 + gates -> h0(t) (recurrent)
//   role 2 L1X: xt1 = Wx1 . h0(t) + bx1
//   role 3 L1H: Wh1 . h1 + gates -> h1(t); epilogue Wo
// Each lane holds ONE weight row (128 packed-f16 dwords) -> ~165 VGPR, the
// 12-wave block fits one CU; all 256 blocks co-resident (required for spins).
// Stage handoff: 8-slot rings in d_ws; relaxed payload stores + threadfence +
// release counter / acquire spin. Blocks p, p+64, p+128, p+192 share an XCD.
// ---------------------------------------------------------------------------

#define NPAIR 64
#define WSLOT 8

#if defined(__has_builtin)
#if __has_builtin(__builtin_amdgcn_fdot2)
#define USE_DOT2 1
#endif
#endif

typedef _Float16 h2_t __attribute__((ext_vector_type(2)));
union H2U { uint32_t u; h2_t h; };
union FU  { uint32_t u; float f; };

__device__ __forceinline__ float bf2f(uint16_t b){ FU v; v.u=(uint32_t)b<<16; return v.f; }
__device__ __forceinline__ uint16_t f2bf(float f){
    FU v; v.f=f; uint32_t r=v.u+0x7fffu+((v.u>>16)&1u); return (uint16_t)(r>>16);
}
__device__ __forceinline__ float sigmoid_f(float x){ return 1.0f/(1.0f+__expf(-x)); }
__device__ __forceinline__ float tanh_f(float x){
    float ax=fabsf(x); float e=__expf(-2.0f*ax);
    float t=(1.0f-e)/(1.0f+e); return x<0.0f?-t:t;
}

// internal packed-pair format: f16x2 when fdot2 exists, else raw bf16x2
__device__ __forceinline__ float dot2acc(uint32_t w, uint32_t v, float acc){
#ifdef USE_DOT2
    H2U a,b; a.u=w; b.u=v;
    return __builtin_amdgcn_fdot2(a.h, b.h, acc, false);
#else
    FU x0,x1,y0,y1;
    x0.u=w<<16; x1.u=w&0xffff0000u; y0.u=v<<16; y1.u=v&0xffff0000u;
    acc=fmaf(x0.f,y0.f,acc); return fmaf(x1.f,y1.f,acc);
#endif
}
__device__ __forceinline__ uint32_t cvt_bfpair(uint32_t raw){
#ifdef USE_DOT2
    FU lo,hi; lo.u=raw<<16; hi.u=raw&0xffff0000u;
    H2U r; r.h[0]=(_Float16)lo.f; r.h[1]=(_Float16)hi.f; return r.u;
#else
    return raw;
#endif
}
__device__ __forceinline__ uint32_t packpair(float lo, float hi){
#ifdef USE_DOT2
    H2U r; r.h[0]=(_Float16)lo; r.h[1]=(_Float16)hi; return r.u;
#else
    return (uint32_t)f2bf(lo) | ((uint32_t)f2bf(hi)<<16);
#endif
}
__device__ __forceinline__ float f16sel(uint32_t w, int hi){
#ifdef USE_DOT2
    H2U u; u.u=w; return (float)u.h[hi];
#else
    FU v; v.u = hi ? (w & 0xffff0000u) : (w << 16); return v.f;
#endif
}

#define DOT256(acc0, acc1, WREG, SRC)                              \
    _Pragma("unroll")                                              \
    for (int c = 0; c < 32; ++c) {                                 \
        uint4 va = ((const uint4*)&SRC[0][0])[c];                  \
        uint4 vb = ((const uint4*)&SRC[1][0])[c];                  \
        acc0 = dot2acc(WREG[4*c+0], va.x, acc0);                   \
        acc1 = dot2acc(WREG[4*c+0], vb.x, acc1);                   \
        acc0 = dot2acc(WREG[4*c+1], va.y, acc0);                   \
        acc1 = dot2acc(WREG[4*c+1], vb.y, acc1);                   \
        acc0 = dot2acc(WREG[4*c+2], va.z, acc0);                   \
        acc1 = dot2acc(WREG[4*c+2], vb.z, acc1);                   \
        acc0 = dot2acc(WREG[4*c+3], va.w, acc0);                   \
        acc1 = dot2acc(WREG[4*c+3], vb.w, acc1);                   \
    }

// Zero counters; detect dtype. bf16 pairs: dword bits[14:7] = low element's
// exponent, clustered in [0x60,0x7C] for uniform(-1/16,1/16) weights.
// fp32: bits[14:7] = uniform mantissa bits (~11% hit rate).
__global__ void probe_init(const uint32_t* __restrict__ w,
                           uint32_t* __restrict__ ctr,
                           uint32_t* __restrict__ flag) {
    int i = threadIdx.x;
    for (int k = i; k < 4096; k += 1024) ctr[k] = 0u;
    if (i == 0) {
        int c = 0;
        for (int j = 0; j < 64; ++j) {
            uint32_t e = (w[j] >> 7) & 0xFFu;
            c += (e >= 0x60u && e <= 0x7Cu) ? 1 : 0;
        }
        flag[0] = (c >= 32) ? 1u : 0u;
    }
}

__global__ void __launch_bounds__(768, 3)
gru_pipe4(const void* __restrict__ xin,
          const void* __restrict__ Wx0, const void* __restrict__ bx0,
          const void* __restrict__ Wh0, const void* __restrict__ bh0,
          const void* __restrict__ Wx1, const void* __restrict__ bx1,
          const void* __restrict__ Wh1, const void* __restrict__ bh1,
          const void* __restrict__ Wo,  const void* __restrict__ bo,
          void* __restrict__ out,
          uint32_t* __restrict__ ws)
{
    const int tid  = threadIdx.x;
    const int pair = blockIdx.x & (NPAIR - 1);
    const int role = blockIdx.x >> 6;

    uint32_t* XR0 = ws;                                   // 64*8*768
    uint32_t* XR1 = XR0 + NPAIR * WSLOT * 768;
    uint32_t* HR0 = XR1 + NPAIR * WSLOT * 768;            // 64*8*256
    uint32_t* CTR = HR0 + NPAIR * WSLOT * 256;            // [4][64] stride 16
    const uint32_t* FLG = CTR + 4096;

    const int isbf = (int)FLG[0];   // written by probe_init (prior kernel)

    const void* Wsel; const void* bsel;
    if      (role == 0) { Wsel = Wx0; bsel = bx0; }
    else if (role == 1) { Wsel = Wh0; bsel = bh0; }
    else if (role == 2) { Wsel = Wx1; bsel = bx1; }
    else                { Wsel = Wh1; bsel = bh1; }

    uint32_t wreg[128];
    float bias;
    if (isbf) {
        const uint32_t* wr = (const uint32_t*)Wsel + tid * 128;
#pragma unroll
        for (int c = 0; c < 128; ++c) wreg[c] = cvt_bfpair(wr[c]);
        bias = bf2f(((const uint16_t*)bsel)[tid]);
    } else {
        const float2* wr = (const float2*)Wsel + tid * 128;
#pragma unroll
        for (int c = 0; c < 128; ++c) { float2 f = wr[c]; wreg[c] = packpair(f.x, f.y); }
        bias = ((const float*)bsel)[tid];
    }

    __shared__ __align__(16) uint32_t in_p[2][128];
    __shared__ __align__(16) uint32_t h16[2][128];
    __shared__ float s_r[2][256], s_z[2][256], s_nx[2][256], s_nh[2][256];

    uint32_t* myctr   = CTR + role * 1024 + pair * 16;
    uint32_t* prodctr = CTR + (role - 1) * 1024 + pair * 16;   // role>=1 only
    uint32_t* consctr = CTR + (role + 1) * 1024 + pair * 16;   // role<=2 only

    if (role == 0 || role == 2) {
        // ------------------------------ X stages ---------------------------
        uint32_t* myring = (role == 0 ? XR0 : XR1) + pair * (WSLOT * 768);
        const uint32_t* srcring = HR0 + pair * (WSLOT * 256);
        const int bglob = pair * 2 + ((tid >> 7) & 1);
        const int i128  = tid & 127;
        uint32_t prod_seen = 0, cons_seen = 0;

        for (int t = 0; t < 1024; ++t) {
            if (role == 2 && prod_seen < (uint32_t)(t + 1)) {
                do {
                    prod_seen = __hip_atomic_load(prodctr, __ATOMIC_ACQUIRE, __HIP_MEMORY_SCOPE_AGENT);
                    if (prod_seen < (uint32_t)(t + 1)) __builtin_amdgcn_s_sleep(2);
                } while (prod_seen < (uint32_t)(t + 1));
            }
            if (t >= WSLOT && cons_seen + (WSLOT - 1) < (uint32_t)t) {   // ring wrap
                do {
                    cons_seen = __hip_atomic_load(consctr, __ATOMIC_ACQUIRE, __HIP_MEMORY_SCOPE_AGENT);
                    if (cons_seen + (WSLOT - 1) < (uint32_t)t) __builtin_amdgcn_s_sleep(2);
                } while (cons_seen + (WSLOT - 1) < (uint32_t)t);
            }
            uint32_t st = 0;
            if (tid < 256) {
                if (role == 0) {
                    if (isbf) {
                        st = cvt_bfpair(((const uint32_t*)xin)[bglob * 131072 + t * 128 + i128]);
                    } else {
                        float2 f = ((const float2*)xin)[bglob * 131072 + t * 128 + i128];
                        st = packpair(f.x, f.y);
                    }
                } else {
                    st = srcring[(t & (WSLOT - 1)) * 256 + tid];   // h0(t) packed
                }
            }
            if (tid < 256) in_p[tid >> 7][i128] = st;   // safe: after C(t-1)
            __syncthreads();                            // A: staged
            float a0 = bias, a1 = bias;
            DOT256(a0, a1, wreg, in_p);
            float p0 = __shfl_xor(a0, 1);
            float p1 = __shfl_xor(a1, 1);
            if (!(tid & 1)) {
                uint32_t* dst = myring + (t & (WSLOT - 1)) * 768;
                __hip_atomic_store(dst + (tid >> 1),       packpair(a0, p0),
                                   __ATOMIC_RELAXED, __HIP_MEMORY_SCOPE_AGENT);
                __hip_atomic_store(dst + 384 + (tid >> 1), packpair(a1, p1),
                                   __ATOMIC_RELAXED, __HIP_MEMORY_SCOPE_AGENT);
            }
            __threadfence();
            __syncthreads();                            // C: all stores fenced
            if (tid == 0)
                __hip_atomic_store(myctr, (uint32_t)(t + 1),
                                   __ATOMIC_RELEASE, __HIP_MEMORY_SCOPE_AGENT);
        }
    } else {
        // ------------------------------ H stages ---------------------------
        const uint32_t* xr = (role == 1 ? XR0 : XR1) + pair * (WSLOT * 768);
        uint32_t* hring = HR0 + pair * (WSLOT * 256);
        float h_reg = 0.0f;
        if (tid < 256) h16[tid >> 7][tid & 127] = 0u;
        __syncthreads();
        uint32_t prod_seen = 0, cons_seen = 0;
        const int g = tid >> 8, col = tid & 255;

        for (int t = 0; t < 1024; ++t) {
            if (prod_seen < (uint32_t)(t + 1)) {
                do {
                    prod_seen = __hip_atomic_load(prodctr, __ATOMIC_ACQUIRE, __HIP_MEMORY_SCOPE_AGENT);
                    if (prod_seen < (uint32_t)(t + 1)) __builtin_amdgcn_s_sleep(2);
                } while (prod_seen < (uint32_t)(t + 1));
            }
            if (role == 1 && t >= WSLOT && cons_seen + (WSLOT - 1) < (uint32_t)t) {
                do {
                    cons_seen = __hip_atomic_load(consctr, __ATOMIC_ACQUIRE, __HIP_MEMORY_SCOPE_AGENT);
                    if (cons_seen + (WSLOT - 1) < (uint32_t)t) __builtin_amdgcn_s_sleep(2);
                } while (cons_seen + (WSLOT - 1) < (uint32_t)t);
            }
            const uint32_t* xs = xr + (t & (WSLOT - 1)) * 768;
            uint32_t xw0 = xs[tid >> 1];            // xt[row tid], batch0
            uint32_t xw1 = xs[384 + (tid >> 1)];    // batch1

            float hacc0 = bias, hacc1 = bias;
            DOT256(hacc0, hacc1, wreg, h16);

            float xt0 = f16sel(xw0, tid & 1);
            float xt1 = f16sel(xw1, tid & 1);
            __syncthreads();                        // A: dots done, s_* free
            if (g == 2) {
                s_nx[0][col] = xt0;   s_nx[1][col] = xt1;
                s_nh[0][col] = hacc0; s_nh[1][col] = hacc1;
            } else if (g == 1) {
                s_z[0][col] = sigmoid_f(xt0 + hacc0);
                s_z[1][col] = sigmoid_f(xt1 + hacc1);
            } else {
                s_r[0][col] = sigmoid_f(xt0 + hacc0);
                s_r[1][col] = sigmoid_f(xt1 + hacc1);
            }
            __syncthreads();                        // B: gate arrays ready
            if (tid < 512) {                        // g = batch index here
                float z = s_z[g][col];
                float r = s_r[g][col];
                float n = tanh_f(s_nx[g][col] + r * s_nh[g][col]);
                h_reg = z * h_reg + (1.0f - z) * n;
            }
            float hp = __shfl_xor(h_reg, 1);
            if (tid < 512 && !(tid & 1)) {
                uint32_t pk = packpair(h_reg, hp);
                h16[g][col >> 1] = pk;
                if (role == 1)
                    __hip_atomic_store(hring + (t & (WSLOT - 1)) * 256 + g * 128 + (col >> 1),
                                       pk, __ATOMIC_RELAXED, __HIP_MEMORY_SCOPE_AGENT);
            }
            if (role == 1) __threadfence();
            __syncthreads();                        // C
            if (tid == 0)
                __hip_atomic_store(myctr, (uint32_t)(t + 1),
                                   __ATOMIC_RELEASE, __HIP_MEMORY_SCOPE_AGENT);
        }

        // ---------------- epilogue: out = h1 . Wo^T + bo (role 3) ----------
        if (role == 3 && tid < 256) {
            const int bb = tid >> 7, j = tid & 127;
            float acc;
            if (isbf) {
                acc = bf2f(((const uint16_t*)bo)[j]);
                const uint32_t* wo = (const uint32_t*)Wo + j * 128;
#pragma unroll 16
                for (int c = 0; c < 128; ++c)
                    acc = dot2acc(cvt_bfpair(wo[c]), h16[bb][c], acc);
                ((uint16_t*)out)[(pair * 2 + bb) * 128 + j] = f2bf(acc);
            } else {
                acc = ((const float*)bo)[j];
                const float2* wo = (const float2*)Wo + j * 128;
#pragma unroll 16
                for (int c = 0; c < 128; ++c) {
                    float2 f = wo[c];
                    acc = dot2acc(packpair(f.x, f.y), h16[bb][c], acc);
                }
                ((float*)out)[(pair * 2 + bb) * 128 + j] = acc;
            }
        }
    }
}

extern "C" void kernel_launch(void* const* d_in, const int* in_sizes, int n_in,
                              void* d_out, int out_size, void* d_ws, size_t ws_size,
                              hipStream_t stream) {
    uint32_t* ws  = (uint32_t*)d_ws;
    uint32_t* CTR = ws + 2 * NPAIR * WSLOT * 768 + NPAIR * WSLOT * 256;
    uint32_t* FLG = CTR + 4096;

    probe_init<<<dim3(1), dim3(1024), 0, stream>>>((const uint32_t*)d_in[1], CTR, FLG);
    gru_pipe4<<<dim3(256), dim3(768), 0, stream>>>(
        d_in[0], d_in[1], d_in[2], d_in[3], d_in[4],
        d_in[5], d_in[6], d_in[7], d_in[8], d_in[9], d_in[10],
        d_out, ws);
}

// Round 3
// 59350.366 us; speedup vs baseline: 1.0367x; 1.0367x over previous
//
#include <hip/hip_runtime.h>
#include <stdint.h>

// ---------------------------------------------------------------------------
// 2-layer GRU, B=128, T=1024, H=IN=256, OUT=128.  Dtype probed on device.
//
// 256 blocks x 768 threads, 4 roles x 64 batch-pairs (2 batches/block):
//   role 0 L0X: Wx0.x_t   role 1 L0H: Wh0.h0+gates
//   role 2 L1X: Wx1.h0    role 3 L1H: Wh1.h1+gates + Wo epilogue
// v3 change: weights held in 8 x u32x16 ext-vectors (SSA values, cannot be
// demoted to scratch) instead of a uint32_t[128] alloca.  Round-2 counters
// showed VGPR_Count=84 -> the 128-dword array had been left in scratch,
// giving VALUBusy 2.5% and 61 ms.  Budget now: 128 wt + ~35 temps <= 170 cap
// from __launch_bounds__(768,3) (3 waves/EU, 512 regs/SIMD).
// ---------------------------------------------------------------------------

#define NPAIR 64
#define WSLOT 8

#if defined(__has_builtin)
#if __has_builtin(__builtin_amdgcn_fdot2)
#define USE_DOT2 1
#endif
#endif

typedef uint32_t u32x16 __attribute__((ext_vector_type(16)));
typedef _Float16 h2_t __attribute__((ext_vector_type(2)));
union H2U { uint32_t u; h2_t h; };
union FU  { uint32_t u; float f; };

__device__ __forceinline__ float bf2f(uint16_t b){ FU v; v.u=(uint32_t)b<<16; return v.f; }
__device__ __forceinline__ uint16_t f2bf(float f){
    FU v; v.f=f; uint32_t r=v.u+0x7fffu+((v.u>>16)&1u); return (uint16_t)(r>>16);
}
__device__ __forceinline__ float sigmoid_f(float x){ return 1.0f/(1.0f+__expf(-x)); }
__device__ __forceinline__ float tanh_f(float x){
    float ax=fabsf(x); float e=__expf(-2.0f*ax);
    float t=(1.0f-e)/(1.0f+e); return x<0.0f?-t:t;
}

__device__ __forceinline__ float dot2acc(uint32_t w, uint32_t v, float acc){
#ifdef USE_DOT2
    H2U a,b; a.u=w; b.u=v;
    return __builtin_amdgcn_fdot2(a.h, b.h, acc, false);
#else
    FU x0,x1,y0,y1;
    x0.u=w<<16; x1.u=w&0xffff0000u; y0.u=v<<16; y1.u=v&0xffff0000u;
    acc=fmaf(x0.f,y0.f,acc); return fmaf(x1.f,y1.f,acc);
#endif
}
__device__ __forceinline__ uint32_t cvt_bfpair(uint32_t raw){
#ifdef USE_DOT2
    FU lo,hi; lo.u=raw<<16; hi.u=raw&0xffff0000u;
    H2U r; r.h[0]=(_Float16)lo.f; r.h[1]=(_Float16)hi.f; return r.u;
#else
    return raw;
#endif
}
__device__ __forceinline__ uint32_t packpair(float lo, float hi){
#ifdef USE_DOT2
    H2U r; r.h[0]=(_Float16)lo; r.h[1]=(_Float16)hi; return r.u;
#else
    return (uint32_t)f2bf(lo) | ((uint32_t)f2bf(hi)<<16);
#endif
}
__device__ __forceinline__ float f16sel(uint32_t w, int hi){
#ifdef USE_DOT2
    H2U u; u.u=w; return (float)u.h[hi];
#else
    FU v; v.u = hi ? (w & 0xffff0000u) : (w << 16); return v.f;
#endif
}

// 16 packed pairs from 16 bf16-pair dwords (explicit constant lanes)
__device__ __forceinline__ u32x16 load16_bf(const uint4* p){
    uint4 a=p[0], b=p[1], c=p[2], d=p[3];
    u32x16 v;
    v[0]=cvt_bfpair(a.x);  v[1]=cvt_bfpair(a.y);  v[2]=cvt_bfpair(a.z);  v[3]=cvt_bfpair(a.w);
    v[4]=cvt_bfpair(b.x);  v[5]=cvt_bfpair(b.y);  v[6]=cvt_bfpair(b.z);  v[7]=cvt_bfpair(b.w);
    v[8]=cvt_bfpair(c.x);  v[9]=cvt_bfpair(c.y);  v[10]=cvt_bfpair(c.z); v[11]=cvt_bfpair(c.w);
    v[12]=cvt_bfpair(d.x); v[13]=cvt_bfpair(d.y); v[14]=cvt_bfpair(d.z); v[15]=cvt_bfpair(d.w);
    return v;
}
// 16 packed pairs from 32 fp32 weights
__device__ __forceinline__ u32x16 load16_f32(const float2* p){
    u32x16 v;
#define LF(i) v[i] = packpair(p[i].x, p[i].y)
    LF(0);LF(1);LF(2);LF(3);LF(4);LF(5);LF(6);LF(7);
    LF(8);LF(9);LF(10);LF(11);LF(12);LF(13);LF(14);LF(15);
#undef LF
    return v;
}

// dual-batch 256-element dot against LDS-broadcast inputs
#define DOTV(acc0, acc1, W, SRC)                                             \
    _Pragma("unroll")                                                        \
    for (int k = 0; k < 8; ++k) {                                            \
        const uint4* pa = ((const uint4*)&SRC[0][0]) + 4*k;                  \
        const uint4* pb = ((const uint4*)&SRC[1][0]) + 4*k;                  \
        _Pragma("unroll")                                                    \
        for (int q = 0; q < 4; ++q) {                                        \
            uint4 va = pa[q], vb = pb[q];                                    \
            acc0 = dot2acc(W[k][4*q+0], va.x, acc0);                         \
            acc1 = dot2acc(W[k][4*q+0], vb.x, acc1);                         \
            acc0 = dot2acc(W[k][4*q+1], va.y, acc0);                         \
            acc1 = dot2acc(W[k][4*q+1], vb.y, acc1);                         \
            acc0 = dot2acc(W[k][4*q+2], va.z, acc0);                         \
            acc1 = dot2acc(W[k][4*q+2], vb.z, acc1);                         \
            acc0 = dot2acc(W[k][4*q+3], va.w, acc0);                         \
            acc1 = dot2acc(W[k][4*q+3], vb.w, acc1);                         \
        }                                                                    \
    }

// Zero counters; detect dtype (bf16 low-element exponent clustering).
__global__ void probe_init(const uint32_t* __restrict__ w,
                           uint32_t* __restrict__ ctr,
                           uint32_t* __restrict__ flag) {
    int i = threadIdx.x;
    for (int k = i; k < 4096; k += 1024) ctr[k] = 0u;
    if (i == 0) {
        int c = 0;
        for (int j = 0; j < 64; ++j) {
            uint32_t e = (w[j] >> 7) & 0xFFu;
            c += (e >= 0x60u && e <= 0x7Cu) ? 1 : 0;
        }
        flag[0] = (c >= 32) ? 1u : 0u;
    }
}

__global__ void __launch_bounds__(768, 3)
gru_pipe4(const void* __restrict__ xin,
          const void* __restrict__ Wx0, const void* __restrict__ bx0,
          const void* __restrict__ Wh0, const void* __restrict__ bh0,
          const void* __restrict__ Wx1, const void* __restrict__ bx1,
          const void* __restrict__ Wh1, const void* __restrict__ bh1,
          const void* __restrict__ Wo,  const void* __restrict__ bo,
          void* __restrict__ out,
          uint32_t* __restrict__ ws)
{
    const int tid  = threadIdx.x;
    const int pair = blockIdx.x & (NPAIR - 1);
    const int role = blockIdx.x >> 6;

    uint32_t* XR0 = ws;
    uint32_t* XR1 = XR0 + NPAIR * WSLOT * 768;
    uint32_t* HR0 = XR1 + NPAIR * WSLOT * 768;
    uint32_t* CTR = HR0 + NPAIR * WSLOT * 256;
    const uint32_t* FLG = CTR + 4096;

    const int isbf = (int)FLG[0];

    const void* Wsel; const void* bsel;
    if      (role == 0) { Wsel = Wx0; bsel = bx0; }
    else if (role == 1) { Wsel = Wh0; bsel = bh0; }
    else if (role == 2) { Wsel = Wx1; bsel = bx1; }
    else                { Wsel = Wh1; bsel = bh1; }

    // weights as 8 SSA vector values (128 dwords) -- cannot be demoted
    u32x16 wv0, wv1, wv2, wv3, wv4, wv5, wv6, wv7;
    float bias;
    if (isbf) {
        const uint4* wr = (const uint4*)Wsel + tid * 32;
        wv0 = load16_bf(wr);      wv1 = load16_bf(wr + 4);
        wv2 = load16_bf(wr + 8);  wv3 = load16_bf(wr + 12);
        wv4 = load16_bf(wr + 16); wv5 = load16_bf(wr + 20);
        wv6 = load16_bf(wr + 24); wv7 = load16_bf(wr + 28);
        bias = bf2f(((const uint16_t*)bsel)[tid]);
    } else {
        const float2* wr = (const float2*)Wsel + tid * 128;
        wv0 = load16_f32(wr);       wv1 = load16_f32(wr + 16);
        wv2 = load16_f32(wr + 32);  wv3 = load16_f32(wr + 48);
        wv4 = load16_f32(wr + 64);  wv5 = load16_f32(wr + 80);
        wv6 = load16_f32(wr + 96);  wv7 = load16_f32(wr + 112);
        bias = ((const float*)bsel)[tid];
    }
    u32x16 wv[8] = {wv0, wv1, wv2, wv3, wv4, wv5, wv6, wv7};

    __shared__ __align__(16) uint32_t in_p[2][128];
    __shared__ __align__(16) uint32_t h16[2][128];
    __shared__ float s_r[2][256], s_z[2][256], s_nx[2][256], s_nh[2][256];

    uint32_t* myctr   = CTR + role * 1024 + pair * 16;
    uint32_t* prodctr = CTR + (role - 1) * 1024 + pair * 16;
    uint32_t* consctr = CTR + (role + 1) * 1024 + pair * 16;

    if (role == 0 || role == 2) {
        // ------------------------------ X stages ---------------------------
        uint32_t* myring = (role == 0 ? XR0 : XR1) + pair * (WSLOT * 768);
        const uint32_t* srcring = HR0 + pair * (WSLOT * 256);
        const int bglob = pair * 2 + ((tid >> 7) & 1);
        const int i128  = tid & 127;
        uint32_t prod_seen = 0, cons_seen = 0;

        for (int t = 0; t < 1024; ++t) {
            if (role == 2 && prod_seen < (uint32_t)(t + 1)) {
                do {
                    prod_seen = __hip_atomic_load(prodctr, __ATOMIC_ACQUIRE, __HIP_MEMORY_SCOPE_AGENT);
                    if (prod_seen < (uint32_t)(t + 1)) __builtin_amdgcn_s_sleep(2);
                } while (prod_seen < (uint32_t)(t + 1));
            }
            if (t >= WSLOT && cons_seen + (WSLOT - 1) < (uint32_t)t) {
                do {
                    cons_seen = __hip_atomic_load(consctr, __ATOMIC_ACQUIRE, __HIP_MEMORY_SCOPE_AGENT);
                    if (cons_seen + (WSLOT - 1) < (uint32_t)t) __builtin_amdgcn_s_sleep(2);
                } while (cons_seen + (WSLOT - 1) < (uint32_t)t);
            }
            uint32_t st = 0;
            if (tid < 256) {
                if (role == 0) {
                    if (isbf) {
                        st = cvt_bfpair(((const uint32_t*)xin)[bglob * 131072 + t * 128 + i128]);
                    } else {
                        float2 f = ((const float2*)xin)[bglob * 131072 + t * 128 + i128];
                        st = packpair(f.x, f.y);
                    }
                } else {
                    st = srcring[(t & (WSLOT - 1)) * 256 + tid];
                }
            }
            if (tid < 256) in_p[tid >> 7][i128] = st;   // safe: after C(t-1)
            __syncthreads();                            // A: staged
            float a0 = bias, a1 = bias;
            DOTV(a0, a1, wv, in_p);
            float p0 = __shfl_xor(a0, 1);
            float p1 = __shfl_xor(a1, 1);
            if (!(tid & 1)) {
                uint32_t* dst = myring + (t & (WSLOT - 1)) * 768;
                __hip_atomic_store(dst + (tid >> 1),       packpair(a0, p0),
                                   __ATOMIC_RELAXED, __HIP_MEMORY_SCOPE_AGENT);
                __hip_atomic_store(dst + 384 + (tid >> 1), packpair(a1, p1),
                                   __ATOMIC_RELAXED, __HIP_MEMORY_SCOPE_AGENT);
            }
            __threadfence();
            __syncthreads();                            // C: stores fenced
            if (tid == 0)
                __hip_atomic_store(myctr, (uint32_t)(t + 1),
                                   __ATOMIC_RELEASE, __HIP_MEMORY_SCOPE_AGENT);
        }
    } else {
        // ------------------------------ H stages ---------------------------
        const uint32_t* xr = (role == 1 ? XR0 : XR1) + pair * (WSLOT * 768);
        uint32_t* hring = HR0 + pair * (WSLOT * 256);
        float h_reg = 0.0f;
        if (tid < 256) h16[tid >> 7][tid & 127] = 0u;
        __syncthreads();
        uint32_t prod_seen = 0, cons_seen = 0;
        const int g = tid >> 8, col = tid & 255;

        for (int t = 0; t < 1024; ++t) {
            if (prod_seen < (uint32_t)(t + 1)) {
                do {
                    prod_seen = __hip_atomic_load(prodctr, __ATOMIC_ACQUIRE, __HIP_MEMORY_SCOPE_AGENT);
                    if (prod_seen < (uint32_t)(t + 1)) __builtin_amdgcn_s_sleep(2);
                } while (prod_seen < (uint32_t)(t + 1));
            }
            if (role == 1 && t >= WSLOT && cons_seen + (WSLOT - 1) < (uint32_t)t) {
                do {
                    cons_seen = __hip_atomic_load(consctr, __ATOMIC_ACQUIRE, __HIP_MEMORY_SCOPE_AGENT);
                    if (cons_seen + (WSLOT - 1) < (uint32_t)t) __builtin_amdgcn_s_sleep(2);
                } while (cons_seen + (WSLOT - 1) < (uint32_t)t);
            }
            const uint32_t* xs = xr + (t & (WSLOT - 1)) * 768;
            uint32_t xw0 = xs[tid >> 1];
            uint32_t xw1 = xs[384 + (tid >> 1)];

            float hacc0 = bias, hacc1 = bias;
            DOTV(hacc0, hacc1, wv, h16);

            float xt0 = f16sel(xw0, tid & 1);
            float xt1 = f16sel(xw1, tid & 1);
            __syncthreads();                        // A: dots done, s_* free
            if (g == 2) {
                s_nx[0][col] = xt0;   s_nx[1][col] = xt1;
                s_nh[0][col] = hacc0; s_nh[1][col] = hacc1;
            } else if (g == 1) {
                s_z[0][col] = sigmoid_f(xt0 + hacc0);
                s_z[1][col] = sigmoid_f(xt1 + hacc1);
            } else {
                s_r[0][col] = sigmoid_f(xt0 + hacc0);
                s_r[1][col] = sigmoid_f(xt1 + hacc1);
            }
            __syncthreads();                        // B: gate arrays ready
            if (tid < 512) {
                float z = s_z[g][col];
                float r = s_r[g][col];
                float n = tanh_f(s_nx[g][col] + r * s_nh[g][col]);
                h_reg = z * h_reg + (1.0f - z) * n;
            }
            float hp = __shfl_xor(h_reg, 1);
            if (tid < 512 && !(tid & 1)) {
                uint32_t pk = packpair(h_reg, hp);
                h16[g][col >> 1] = pk;
                if (role == 1)
                    __hip_atomic_store(hring + (t & (WSLOT - 1)) * 256 + g * 128 + (col >> 1),
                                       pk, __ATOMIC_RELAXED, __HIP_MEMORY_SCOPE_AGENT);
            }
            if (role == 1) __threadfence();
            __syncthreads();                        // C
            if (tid == 0)
                __hip_atomic_store(myctr, (uint32_t)(t + 1),
                                   __ATOMIC_RELEASE, __HIP_MEMORY_SCOPE_AGENT);
        }

        // ---------------- epilogue: out = h1 . Wo^T + bo (role 3) ----------
        if (role == 3 && tid < 256) {
            const int bb = tid >> 7, j = tid & 127;
            float acc;
            if (isbf) {
                acc = bf2f(((const uint16_t*)bo)[j]);
                const uint32_t* wo = (const uint32_t*)Wo + j * 128;
#pragma unroll 16
                for (int c = 0; c < 128; ++c)
                    acc = dot2acc(cvt_bfpair(wo[c]), h16[bb][c], acc);
                ((uint16_t*)out)[(pair * 2 + bb) * 128 + j] = f2bf(acc);
            } else {
                acc = ((const float*)bo)[j];
                const float2* wo = (const float2*)Wo + j * 128;
#pragma unroll 16
                for (int c = 0; c < 128; ++c) {
                    float2 f = wo[c];
                    acc = dot2acc(packpair(f.x, f.y), h16[bb][c], acc);
                }
                ((float*)out)[(pair * 2 + bb) * 128 + j] = acc;
            }
        }
    }
}

extern "C" void kernel_launch(void* const* d_in, const int* in_sizes, int n_in,
                              void* d_out, int out_size, void* d_ws, size_t ws_size,
                              hipStream_t stream) {
    uint32_t* ws  = (uint32_t*)d_ws;
    uint32_t* CTR = ws + 2 * NPAIR * WSLOT * 768 + NPAIR * WSLOT * 256;
    uint32_t* FLG = CTR + 4096;

    probe_init<<<dim3(1), dim3(1024), 0, stream>>>((const uint32_t*)d_in[1], CTR, FLG);
    gru_pipe4<<<dim3(256), dim3(768), 0, stream>>>(
        d_in[0], d_in[1], d_in[2], d_in[3], d_in[4],
        d_in[5], d_in[6], d_in[7], d_in[8], d_in[9], d_in[10],
        d_out, ws);
}

// Round 4
// 37333.691 us; speedup vs baseline: 1.6480x; 1.5897x over previous
//
#include <hip/hip_runtime.h>
#include <stdint.h>

// ---------------------------------------------------------------------------
// 2-layer GRU, B=128, T=1024, H=IN=256, OUT=128.  Dtype probed on device.
//
// v4: 256 blocks x 512 threads (8 waves -> 2 waves/SIMD -> 256-VGPR cap; the
// previous 768-thread shape forced a 170 cap and the RA spilled the weights,
// VGPR_Count=84, VALUBusy 2.5%).  4 roles x 64 batch-pairs:
//   role0 L0X: Wx0.x_t    role1 L0H: Wh0.h0 + gates -> h0
//   role2 L1X: Wx1.h0     role3 L1H: Wh1.h1 + gates -> h1; Wo epilogue
// Lane L: unit p=L>>1, col-half hs=L&1; holds the hs-half of rows
// {p, p+256, p+512} = 12 named u32x16 SSA vecs (192 dwords).  Full row sums
// via shfl_xor(1); gates computed in-register (no LDS gate arrays); ONE
// barrier/step with double-buffered LDS h/input.  Ring handoff in d_ws with
// one-step-delayed flag certification so the per-step fence waits on stores
// issued a full step earlier (~free).  xt/h0 payloads preloaded one step
// ahead when the producer flag allows (steady state: always).
// ---------------------------------------------------------------------------

#define NPAIR 64
#define WSLOT 4

// ws layout in dwords
#define XR0_OFF 0                     // f32 [64][4][1536]
#define XR1_OFF 393216                // f32 [64][4][1536]
#define HR0_OFF 786432                // u32 [64][4][256]
#define CTR_OFF 851968                // u32 [4][64][16]
#define FLG_OFF 856064

#if defined(__has_builtin)
#if __has_builtin(__builtin_amdgcn_fdot2)
#define USE_DOT2 1
#endif
#endif

typedef uint32_t u32x16 __attribute__((ext_vector_type(16)));
typedef _Float16 h2_t __attribute__((ext_vector_type(2)));
union H2U { uint32_t u; h2_t h; };
union FU  { uint32_t u; float f; };

__device__ __forceinline__ float bf2f(uint16_t b){ FU v; v.u=(uint32_t)b<<16; return v.f; }
__device__ __forceinline__ uint16_t f2bf(float f){
    FU v; v.f=f; uint32_t r=v.u+0x7fffu+((v.u>>16)&1u); return (uint16_t)(r>>16);
}
__device__ __forceinline__ float sigmoid_f(float x){ return 1.0f/(1.0f+__expf(-x)); }
__device__ __forceinline__ float tanh_f(float x){
    float ax=fabsf(x); float e=__expf(-2.0f*ax);
    float t=(1.0f-e)/(1.0f+e); return x<0.0f?-t:t;
}
__device__ __forceinline__ float dot2acc(uint32_t w, uint32_t v, float acc){
#ifdef USE_DOT2
    H2U a,b; a.u=w; b.u=v;
    return __builtin_amdgcn_fdot2(a.h, b.h, acc, false);
#else
    FU x0,x1,y0,y1;
    x0.u=w<<16; x1.u=w&0xffff0000u; y0.u=v<<16; y1.u=v&0xffff0000u;
    acc=fmaf(x0.f,y0.f,acc); return fmaf(x1.f,y1.f,acc);
#endif
}
__device__ __forceinline__ uint32_t cvt_bfpair(uint32_t raw){
#ifdef USE_DOT2
    FU lo,hi; lo.u=raw<<16; hi.u=raw&0xffff0000u;
    H2U r; r.h[0]=(_Float16)lo.f; r.h[1]=(_Float16)hi.f; return r.u;
#else
    return raw;
#endif
}
__device__ __forceinline__ uint32_t packpair(float lo, float hi){
#ifdef USE_DOT2
    H2U r; r.h[0]=(_Float16)lo; r.h[1]=(_Float16)hi; return r.u;
#else
    return (uint32_t)f2bf(lo) | ((uint32_t)f2bf(hi)<<16);
#endif
}
__device__ __forceinline__ u32x16 load16_bf(const uint4* p){
    uint4 a=p[0], b=p[1], c=p[2], d=p[3];
    u32x16 v;
    v[0]=cvt_bfpair(a.x);  v[1]=cvt_bfpair(a.y);  v[2]=cvt_bfpair(a.z);  v[3]=cvt_bfpair(a.w);
    v[4]=cvt_bfpair(b.x);  v[5]=cvt_bfpair(b.y);  v[6]=cvt_bfpair(b.z);  v[7]=cvt_bfpair(b.w);
    v[8]=cvt_bfpair(c.x);  v[9]=cvt_bfpair(c.y);  v[10]=cvt_bfpair(c.z); v[11]=cvt_bfpair(c.w);
    v[12]=cvt_bfpair(d.x); v[13]=cvt_bfpair(d.y); v[14]=cvt_bfpair(d.z); v[15]=cvt_bfpair(d.w);
    return v;
}
__device__ __forceinline__ u32x16 load16_f32(const float2* p){
    u32x16 v;
#define LF(i) v[i] = packpair(p[i].x, p[i].y)
    LF(0);LF(1);LF(2);LF(3);LF(4);LF(5);LF(6);LF(7);
    LF(8);LF(9);LF(10);LF(11);LF(12);LF(13);LF(14);LF(15);
#undef LF
    return v;
}

// 16 dwords of input (one quarter of this lane's half) against 3 named
// 16-dword weight vectors; dual batch.
#define DOT16(WR, WZ, WN, G)                                                      \
    _Pragma("unroll")                                                             \
    for (int q = 0; q < 4; ++q) {                                                 \
        uint4 va = pa[4*(G)+q], vb = pb[4*(G)+q];                                 \
        ar0 = dot2acc(WR[4*q+0], va.x, ar0); ar1 = dot2acc(WR[4*q+0], vb.x, ar1); \
        az0 = dot2acc(WZ[4*q+0], va.x, az0); az1 = dot2acc(WZ[4*q+0], vb.x, az1); \
        an0 = dot2acc(WN[4*q+0], va.x, an0); an1 = dot2acc(WN[4*q+0], vb.x, an1); \
        ar0 = dot2acc(WR[4*q+1], va.y, ar0); ar1 = dot2acc(WR[4*q+1], vb.y, ar1); \
        az0 = dot2acc(WZ[4*q+1], va.y, az0); az1 = dot2acc(WZ[4*q+1], vb.y, az1); \
        an0 = dot2acc(WN[4*q+1], va.y, an0); an1 = dot2acc(WN[4*q+1], vb.y, an1); \
        ar0 = dot2acc(WR[4*q+2], va.z, ar0); ar1 = dot2acc(WR[4*q+2], vb.z, ar1); \
        az0 = dot2acc(WZ[4*q+2], va.z, az0); az1 = dot2acc(WZ[4*q+2], vb.z, az1); \
        an0 = dot2acc(WN[4*q+2], va.z, an0); an1 = dot2acc(WN[4*q+2], vb.z, an1); \
        ar0 = dot2acc(WR[4*q+3], va.w, ar0); ar1 = dot2acc(WR[4*q+3], vb.w, ar1); \
        az0 = dot2acc(WZ[4*q+3], va.w, az0); az1 = dot2acc(WZ[4*q+3], vb.w, az1); \
        an0 = dot2acc(WN[4*q+3], va.w, an0); an1 = dot2acc(WN[4*q+3], vb.w, an1); \
    }

__global__ void probe_init(const uint32_t* __restrict__ w,
                           uint32_t* __restrict__ ctr,
                           uint32_t* __restrict__ flag) {
    int i = threadIdx.x;
    for (int k = i; k < 4096; k += 1024) ctr[k] = 0u;
    if (i == 0) {
        int c = 0;
        for (int j = 0; j < 64; ++j) {
            uint32_t e = (w[j] >> 7) & 0xFFu;
            c += (e >= 0x60u && e <= 0x7Cu) ? 1 : 0;
        }
        flag[0] = (c >= 32) ? 1u : 0u;
    }
}

__global__ void __launch_bounds__(512, 2)
gru5(const void* __restrict__ xin,
     const void* __restrict__ Wx0, const void* __restrict__ bx0,
     const void* __restrict__ Wh0, const void* __restrict__ bh0,
     const void* __restrict__ Wx1, const void* __restrict__ bx1,
     const void* __restrict__ Wh1, const void* __restrict__ bh1,
     const void* __restrict__ Wo,  const void* __restrict__ bo,
     void* __restrict__ out,
     uint32_t* __restrict__ ws)
{
    const int tid  = threadIdx.x;
    const int pair = blockIdx.x & (NPAIR - 1);
    const int role = blockIdx.x >> 6;
    const int p    = tid >> 1;       // hidden unit / row base
    const int hs   = tid & 1;        // column half (and gate-batch index)

    float*    XRING0 = (float*)(ws + XR0_OFF) + pair * 6144;
    float*    XRING1 = (float*)(ws + XR1_OFF) + pair * 6144;
    uint32_t* HRING  = ws + HR0_OFF + pair * 1024;
    uint32_t* CTR    = ws + CTR_OFF;
    const int isbf   = (int)ws[FLG_OFF];

    uint32_t* myctr   = CTR + role * 1024 + pair * 16;
    uint32_t* prodctr = CTR + (role - 1) * 1024 + pair * 16;   // role>=1
    uint32_t* consctr = CTR + (role + 1) * 1024 + pair * 16;   // role<=2

    const void* Wsel; const void* bsel;
    if      (role == 0) { Wsel = Wx0; bsel = bx0; }
    else if (role == 1) { Wsel = Wh0; bsel = bh0; }
    else if (role == 2) { Wsel = Wx1; bsel = bx1; }
    else                { Wsel = Wh1; bsel = bh1; }

    // 12 named SSA weight vectors: half-rows of {p, p+256, p+512}
    u32x16 wr0,wr1,wr2,wr3, wz0,wz1,wz2,wz3, wn0,wn1,wn2,wn3;
    float br, bz, bn;
    if (isbf) {
        const uint4* W4 = (const uint4*)Wsel;
        const uint4* r0 = W4 + (size_t)p * 32 + hs * 16;
        const uint4* r1 = W4 + (size_t)(p + 256) * 32 + hs * 16;
        const uint4* r2 = W4 + (size_t)(p + 512) * 32 + hs * 16;
        wr0=load16_bf(r0);    wr1=load16_bf(r0+4);  wr2=load16_bf(r0+8);  wr3=load16_bf(r0+12);
        wz0=load16_bf(r1);    wz1=load16_bf(r1+4);  wz2=load16_bf(r1+8);  wz3=load16_bf(r1+12);
        wn0=load16_bf(r2);    wn1=load16_bf(r2+4);  wn2=load16_bf(r2+8);  wn3=load16_bf(r2+12);
        const uint16_t* bs = (const uint16_t*)bsel;
        br = bf2f(bs[p]); bz = bf2f(bs[p+256]); bn = bf2f(bs[p+512]);
    } else {
        const float2* W2 = (const float2*)Wsel;
        const float2* r0 = W2 + (size_t)p * 128 + hs * 64;
        const float2* r1 = W2 + (size_t)(p + 256) * 128 + hs * 64;
        const float2* r2 = W2 + (size_t)(p + 512) * 128 + hs * 64;
        wr0=load16_f32(r0);    wr1=load16_f32(r0+16); wr2=load16_f32(r0+32); wr3=load16_f32(r0+48);
        wz0=load16_f32(r1);    wz1=load16_f32(r1+16); wz2=load16_f32(r1+32); wz3=load16_f32(r1+48);
        wn0=load16_f32(r2);    wn1=load16_f32(r2+16); wn2=load16_f32(r2+32); wn3=load16_f32(r2+48);
        const float* bs = (const float*)bsel;
        br = bs[p]; bz = bs[p+256]; bn = bs[p+512];
    }

    // X roles: input staging (double-buffered).  H roles: h state (dbl-buf).
    __shared__ __align__(16) uint32_t sbuf[2][2][128];

    if (role == 0 || role == 2) {
        // ------------------------------ X stages ---------------------------
        const uint32_t* xs32 = (const uint32_t*)xin;
        const float2*   xsf  = (const float2*)xin;
        const int bglob = pair * 2 + (tid >> 7);
        const int i128  = tid & 127;
        uint32_t xpref = 0, nxt = 0; bool have = false;
        if (role == 0 && tid < 256) {
            if (isbf) xpref = cvt_bfpair(xs32[(size_t)bglob * 131072 + i128]);
            else { float2 f = xsf[(size_t)bglob * 131072 + i128]; xpref = packpair(f.x, f.y); }
        }
        float* outring = (role == 0) ? XRING0 : XRING1;
        uint32_t prog_seen = 0;

        for (int t = 0; t < 1024; ++t) {
            if (t >= WSLOT && prog_seen + (WSLOT - 1) < (uint32_t)t) {
                do { prog_seen = __hip_atomic_load(consctr, __ATOMIC_RELAXED, __HIP_MEMORY_SCOPE_AGENT);
                     if (prog_seen + (WSLOT - 1) < (uint32_t)t) __builtin_amdgcn_s_sleep(2);
                } while (prog_seen + (WSLOT - 1) < (uint32_t)t);
            }
            __threadfence();                        // certifies ring stores(t-1); ~free
            if (tid < 256) {
                uint32_t pk;
                if (role == 0) pk = xpref;
                else {
                    if (have) pk = nxt;
                    else {
                        uint32_t c;
                        do { c = __hip_atomic_load(prodctr, __ATOMIC_ACQUIRE, __HIP_MEMORY_SCOPE_AGENT);
                             if (c < (uint32_t)(t + 1)) __builtin_amdgcn_s_sleep(2);
                        } while (c < (uint32_t)(t + 1));
                        pk = __hip_atomic_load(HRING + (t & 3) * 256 + tid,
                                               __ATOMIC_RELAXED, __HIP_MEMORY_SCOPE_AGENT);
                    }
                }
                sbuf[t & 1][tid >> 7][i128] = pk;
            }
            __syncthreads();
            if (tid == 0)
                __hip_atomic_store(myctr, (uint32_t)t, __ATOMIC_RELEASE, __HIP_MEMORY_SCOPE_AGENT);
            if (tid < 256 && t < 1023) {           // prefetch t+1
                if (role == 0) {
                    if (isbf) xpref = cvt_bfpair(xs32[(size_t)bglob * 131072 + (t+1)*128 + i128]);
                    else { float2 f = xsf[(size_t)bglob * 131072 + (t+1)*128 + i128]; xpref = packpair(f.x, f.y); }
                } else {
                    uint32_t c = __hip_atomic_load(prodctr, __ATOMIC_RELAXED, __HIP_MEMORY_SCOPE_AGENT);
                    have = (c >= (uint32_t)(t + 2));
                    if (have) nxt = __hip_atomic_load(HRING + ((t+1) & 3) * 256 + tid,
                                                      __ATOMIC_RELAXED, __HIP_MEMORY_SCOPE_AGENT);
                }
            }
            float ar0=0,ar1=0,az0=0,az1=0,an0=0,an1=0;
            {
                const uint4* pa = ((const uint4*)&sbuf[t & 1][0][0]) + hs * 16;
                const uint4* pb = pa + 32;
                DOT16(wr0,wz0,wn0,0); DOT16(wr1,wz1,wn1,1);
                DOT16(wr2,wz2,wn2,2); DOT16(wr3,wz3,wn3,3);
            }
            float R0 = ar0 + __shfl_xor(ar0,1), R1 = ar1 + __shfl_xor(ar1,1);
            float Z0 = az0 + __shfl_xor(az0,1), Z1 = az1 + __shfl_xor(az1,1);
            float N0 = an0 + __shfl_xor(an0,1), N1 = an1 + __shfl_xor(an1,1);
            float sr = (hs ? R1 : R0) + br;
            float sz = (hs ? Z1 : Z0) + bz;
            float sn = (hs ? N1 : N0) + bn;
            float* d = outring + (t & 3) * 1536;
            __hip_atomic_store(d + 2*p + hs,        sr, __ATOMIC_RELAXED, __HIP_MEMORY_SCOPE_AGENT);
            __hip_atomic_store(d + 512 + 2*p + hs,  sz, __ATOMIC_RELAXED, __HIP_MEMORY_SCOPE_AGENT);
            __hip_atomic_store(d + 1024 + 2*p + hs, sn, __ATOMIC_RELAXED, __HIP_MEMORY_SCOPE_AGENT);
        }
        __threadfence(); __syncthreads();
        if (tid == 0)
            __hip_atomic_store(myctr, 1024u, __ATOMIC_RELEASE, __HIP_MEMORY_SCOPE_AGENT);
    } else {
        // ------------------------------ H stages ---------------------------
        const float* xrng = (role == 1) ? XRING0 : XRING1;
        float h_reg = 0.0f;
        if (tid < 256) ((uint32_t*)sbuf)[tid] = 0u;     // zero buf0
        bool have = false; float nr=0, nz=0, nn=0;
        uint32_t prog_seen = 0;

        for (int t = 0; t < 1024; ++t) {
            if (role == 1 && t >= WSLOT && prog_seen + (WSLOT - 1) < (uint32_t)t) {
                do { prog_seen = __hip_atomic_load(consctr, __ATOMIC_RELAXED, __HIP_MEMORY_SCOPE_AGENT);
                     if (prog_seen + (WSLOT - 1) < (uint32_t)t) __builtin_amdgcn_s_sleep(2);
                } while (prog_seen + (WSLOT - 1) < (uint32_t)t);
            }
            __threadfence();                       // certifies h-ring stores(t-1)
            float xr, xz, xn;
            if (have) { xr = nr; xz = nz; xn = nn; }
            else {
                uint32_t c;
                do { c = __hip_atomic_load(prodctr, __ATOMIC_ACQUIRE, __HIP_MEMORY_SCOPE_AGENT);
                     if (c < (uint32_t)(t + 1)) __builtin_amdgcn_s_sleep(2);
                } while (c < (uint32_t)(t + 1));
                const float* s = xrng + (t & 3) * 1536;
                xr = __hip_atomic_load(s + 2*p + hs,        __ATOMIC_RELAXED, __HIP_MEMORY_SCOPE_AGENT);
                xz = __hip_atomic_load(s + 512 + 2*p + hs,  __ATOMIC_RELAXED, __HIP_MEMORY_SCOPE_AGENT);
                xn = __hip_atomic_load(s + 1024 + 2*p + hs, __ATOMIC_RELAXED, __HIP_MEMORY_SCOPE_AGENT);
            }
            __syncthreads();                       // h writes(t-1) visible; all fenced
            if (tid == 0)
                __hip_atomic_store(myctr, (uint32_t)t, __ATOMIC_RELEASE, __HIP_MEMORY_SCOPE_AGENT);
            if (t < 1023) {                        // preload xt(t+1)
                uint32_t c = __hip_atomic_load(prodctr, __ATOMIC_RELAXED, __HIP_MEMORY_SCOPE_AGENT);
                have = (c >= (uint32_t)(t + 2));
                if (have) {
                    const float* s = xrng + ((t + 1) & 3) * 1536;
                    nr = __hip_atomic_load(s + 2*p + hs,        __ATOMIC_RELAXED, __HIP_MEMORY_SCOPE_AGENT);
                    nz = __hip_atomic_load(s + 512 + 2*p + hs,  __ATOMIC_RELAXED, __HIP_MEMORY_SCOPE_AGENT);
                    nn = __hip_atomic_load(s + 1024 + 2*p + hs, __ATOMIC_RELAXED, __HIP_MEMORY_SCOPE_AGENT);
                }
            } else have = false;
            float ar0=0,ar1=0,az0=0,az1=0,an0=0,an1=0;
            {
                const uint4* pa = ((const uint4*)&sbuf[t & 1][0][0]) + hs * 16;
                const uint4* pb = pa + 32;
                DOT16(wr0,wz0,wn0,0); DOT16(wr1,wz1,wn1,1);
                DOT16(wr2,wz2,wn2,2); DOT16(wr3,wz3,wn3,3);
            }
            float R0 = ar0 + __shfl_xor(ar0,1), R1 = ar1 + __shfl_xor(ar1,1);
            float Z0 = az0 + __shfl_xor(az0,1), Z1 = az1 + __shfl_xor(az1,1);
            float N0 = an0 + __shfl_xor(an0,1), N1 = an1 + __shfl_xor(an1,1);
            float r = sigmoid_f(xr + (hs ? R1 : R0) + br);
            float z = sigmoid_f(xz + (hs ? Z1 : Z0) + bz);
            float n = tanh_f(xn + r * ((hs ? N1 : N0) + bn));
            h_reg = z * h_reg + (1.0f - z) * n;
            float hp = __shfl_xor(h_reg, 2);
            if (!(tid & 2)) {                      // p even: pack (h[p], h[p+1])
                uint32_t pk = packpair(h_reg, hp);
                sbuf[(t + 1) & 1][hs][p >> 1] = pk;
                if (role == 1)
                    __hip_atomic_store(HRING + (t & 3) * 256 + hs * 128 + (p >> 1), pk,
                                       __ATOMIC_RELAXED, __HIP_MEMORY_SCOPE_AGENT);
            }
        }
        __threadfence(); __syncthreads();
        if (tid == 0)
            __hip_atomic_store(myctr, 1024u, __ATOMIC_RELEASE, __HIP_MEMORY_SCOPE_AGENT);

        // ---------------- epilogue (role 3): out = h1.Wo^T + bo ------------
        if (role == 3 && tid < 256) {
            const int j = tid >> 1, bb = tid & 1;
            const uint32_t* hv = &sbuf[0][bb][0];   // final h1 (buf 1024&1 = 0)
            float acc;
            if (isbf) {
                acc = bf2f(((const uint16_t*)bo)[j]);
                const uint32_t* wo = (const uint32_t*)Wo + j * 128;
#pragma unroll 8
                for (int c = 0; c < 128; ++c)
                    acc = dot2acc(cvt_bfpair(wo[c]), hv[c], acc);
                ((uint16_t*)out)[(pair * 2 + bb) * 128 + j] = f2bf(acc);
            } else {
                acc = ((const float*)bo)[j];
                const float2* wo = (const float2*)Wo + j * 128;
#pragma unroll 8
                for (int c = 0; c < 128; ++c) {
                    float2 f = wo[c];
                    acc = dot2acc(packpair(f.x, f.y), hv[c], acc);
                }
                ((float*)out)[(pair * 2 + bb) * 128 + j] = acc;
            }
        }
    }
}

extern "C" void kernel_launch(void* const* d_in, const int* in_sizes, int n_in,
                              void* d_out, int out_size, void* d_ws, size_t ws_size,
                              hipStream_t stream) {
    uint32_t* ws  = (uint32_t*)d_ws;
    uint32_t* CTR = ws + CTR_OFF;
    uint32_t* FLG = ws + FLG_OFF;

    probe_init<<<dim3(1), dim3(1024), 0, stream>>>((const uint32_t*)d_in[1], CTR, FLG);
    gru5<<<dim3(256), dim3(512), 0, stream>>>(
        d_in[0], d_in[1], d_in[2], d_in[3], d_in[4],
        d_in[5], d_in[6], d_in[7], d_in[8], d_in[9], d_in[10],
        d_out, ws);
}

// Round 5
// 3032.752 us; speedup vs baseline: 20.2875x; 12.3102x over previous
//
#include <hip/hip_runtime.h>
#include <stdint.h>

// ---------------------------------------------------------------------------
// 2-layer GRU, B=128, T=1024, H=IN=256, OUT=128.  Dtype probed on device.
//
// v5: same 4-stage spin-pipeline as v4 (256 blocks x 512 thr, roles
// L0X/L0H/L1X/L1H x 64 batch-pairs, weights register-resident, one
// barrier/step) but ALL cross-block sync is RELAXED agent-scope (per-op sc1,
// MALL-coherent).  v4 used __threadfence + ACQUIRE spins: every step/poll
// emitted buffer_wbl2/buffer_inv (cache-WIDE L2 flushes) -> 96% wait time,
// weights evicted (FETCH 539 MB), 37 ms.  Ordering now: payload sc1 stores ->
// vmcnt drain at __syncthreads -> relaxed flag store; consumer polls flag
// (relaxed), branches on value (load complete => payload already at MALL).
// LDS: column-half hs=1 skewed +4 dwords so the wave's two broadcast rows
// hit disjoint bank quads (kills 2.7e8 conflict cycles).
// ---------------------------------------------------------------------------

#define NPAIR 64
#define WSLOT 4

// ws layout in dwords
#define XR0_OFF 0                     // f32 [64][4][1536]
#define XR1_OFF 393216                // f32 [64][4][1536]
#define HR0_OFF 786432                // u32 [64][4][256]
#define CTR_OFF 851968                // u32 [4][64][16]
#define FLG_OFF 856064

#if defined(__has_builtin)
#if __has_builtin(__builtin_amdgcn_fdot2)
#define USE_DOT2 1
#endif
#endif

typedef uint32_t u32x16 __attribute__((ext_vector_type(16)));
typedef _Float16 h2_t __attribute__((ext_vector_type(2)));
union H2U { uint32_t u; h2_t h; };
union FU  { uint32_t u; float f; };

__device__ __forceinline__ float bf2f(uint16_t b){ FU v; v.u=(uint32_t)b<<16; return v.f; }
__device__ __forceinline__ uint16_t f2bf(float f){
    FU v; v.f=f; uint32_t r=v.u+0x7fffu+((v.u>>16)&1u); return (uint16_t)(r>>16);
}
__device__ __forceinline__ float sigmoid_f(float x){ return 1.0f/(1.0f+__expf(-x)); }
__device__ __forceinline__ float tanh_f(float x){
    float ax=fabsf(x); float e=__expf(-2.0f*ax);
    float t=(1.0f-e)/(1.0f+e); return x<0.0f?-t:t;
}
__device__ __forceinline__ float dot2acc(uint32_t w, uint32_t v, float acc){
#ifdef USE_DOT2
    H2U a,b; a.u=w; b.u=v;
    return __builtin_amdgcn_fdot2(a.h, b.h, acc, false);
#else
    FU x0,x1,y0,y1;
    x0.u=w<<16; x1.u=w&0xffff0000u; y0.u=v<<16; y1.u=v&0xffff0000u;
    acc=fmaf(x0.f,y0.f,acc); return fmaf(x1.f,y1.f,acc);
#endif
}
__device__ __forceinline__ uint32_t cvt_bfpair(uint32_t raw){
#ifdef USE_DOT2
    FU lo,hi; lo.u=raw<<16; hi.u=raw&0xffff0000u;
    H2U r; r.h[0]=(_Float16)lo.f; r.h[1]=(_Float16)hi.f; return r.u;
#else
    return raw;
#endif
}
__device__ __forceinline__ uint32_t packpair(float lo, float hi){
#ifdef USE_DOT2
    H2U r; r.h[0]=(_Float16)lo; r.h[1]=(_Float16)hi; return r.u;
#else
    return (uint32_t)f2bf(lo) | ((uint32_t)f2bf(hi)<<16);
#endif
}
__device__ __forceinline__ u32x16 load16_bf(const uint4* p){
    uint4 a=p[0], b=p[1], c=p[2], d=p[3];
    u32x16 v;
    v[0]=cvt_bfpair(a.x);  v[1]=cvt_bfpair(a.y);  v[2]=cvt_bfpair(a.z);  v[3]=cvt_bfpair(a.w);
    v[4]=cvt_bfpair(b.x);  v[5]=cvt_bfpair(b.y);  v[6]=cvt_bfpair(b.z);  v[7]=cvt_bfpair(b.w);
    v[8]=cvt_bfpair(c.x);  v[9]=cvt_bfpair(c.y);  v[10]=cvt_bfpair(c.z); v[11]=cvt_bfpair(c.w);
    v[12]=cvt_bfpair(d.x); v[13]=cvt_bfpair(d.y); v[14]=cvt_bfpair(d.z); v[15]=cvt_bfpair(d.w);
    return v;
}
__device__ __forceinline__ u32x16 load16_f32(const float2* p){
    u32x16 v;
#define LF(i) v[i] = packpair(p[i].x, p[i].y)
    LF(0);LF(1);LF(2);LF(3);LF(4);LF(5);LF(6);LF(7);
    LF(8);LF(9);LF(10);LF(11);LF(12);LF(13);LF(14);LF(15);
#undef LF
    return v;
}

#define RLX_LD(p)    __hip_atomic_load((p),        __ATOMIC_RELAXED, __HIP_MEMORY_SCOPE_AGENT)
#define RLX_ST(p,v)  __hip_atomic_store((p), (v),  __ATOMIC_RELAXED, __HIP_MEMORY_SCOPE_AGENT)

// 16 dwords of input (one quarter of this lane's half) vs 3 weight vecs
#define DOT16(WR, WZ, WN, G)                                                      \
    _Pragma("unroll")                                                             \
    for (int q = 0; q < 4; ++q) {                                                 \
        uint4 va = pa[4*(G)+q], vb = pb[4*(G)+q];                                 \
        ar0 = dot2acc(WR[4*q+0], va.x, ar0); ar1 = dot2acc(WR[4*q+0], vb.x, ar1); \
        az0 = dot2acc(WZ[4*q+0], va.x, az0); az1 = dot2acc(WZ[4*q+0], vb.x, az1); \
        an0 = dot2acc(WN[4*q+0], va.x, an0); an1 = dot2acc(WN[4*q+0], vb.x, an1); \
        ar0 = dot2acc(WR[4*q+1], va.y, ar0); ar1 = dot2acc(WR[4*q+1], vb.y, ar1); \
        az0 = dot2acc(WZ[4*q+1], va.y, az0); az1 = dot2acc(WZ[4*q+1], vb.y, az1); \
        an0 = dot2acc(WN[4*q+1], va.y, an0); an1 = dot2acc(WN[4*q+1], vb.y, an1); \
        ar0 = dot2acc(WR[4*q+2], va.z, ar0); ar1 = dot2acc(WR[4*q+2], vb.z, ar1); \
        az0 = dot2acc(WZ[4*q+2], va.z, az0); az1 = dot2acc(WZ[4*q+2], vb.z, az1); \
        an0 = dot2acc(WN[4*q+2], va.z, an0); an1 = dot2acc(WN[4*q+2], vb.z, an1); \
        ar0 = dot2acc(WR[4*q+3], va.w, ar0); ar1 = dot2acc(WR[4*q+3], vb.w, ar1); \
        az0 = dot2acc(WZ[4*q+3], va.w, az0); az1 = dot2acc(WZ[4*q+3], vb.w, az1); \
        an0 = dot2acc(WN[4*q+3], va.w, an0); an1 = dot2acc(WN[4*q+3], vb.w, an1); \
    }

__global__ void probe_init(const uint32_t* __restrict__ w,
                           uint32_t* __restrict__ ctr,
                           uint32_t* __restrict__ flag) {
    int i = threadIdx.x;
    for (int k = i; k < 4096; k += 1024) ctr[k] = 0u;
    if (i == 0) {
        int c = 0;
        for (int j = 0; j < 64; ++j) {
            uint32_t e = (w[j] >> 7) & 0xFFu;
            c += (e >= 0x60u && e <= 0x7Cu) ? 1 : 0;
        }
        flag[0] = (c >= 32) ? 1u : 0u;
    }
}

__global__ void __launch_bounds__(512, 2)
gru6(const void* __restrict__ xin,
     const void* __restrict__ Wx0, const void* __restrict__ bx0,
     const void* __restrict__ Wh0, const void* __restrict__ bh0,
     const void* __restrict__ Wx1, const void* __restrict__ bx1,
     const void* __restrict__ Wh1, const void* __restrict__ bh1,
     const void* __restrict__ Wo,  const void* __restrict__ bo,
     void* __restrict__ out,
     uint32_t* __restrict__ ws)
{
    const int tid  = threadIdx.x;
    const int pair = blockIdx.x & (NPAIR - 1);
    const int role = blockIdx.x >> 6;
    const int p    = tid >> 1;       // hidden unit / row base
    const int hs   = tid & 1;        // column half (and gate-batch index)

    float*    XRING0 = (float*)(ws + XR0_OFF) + pair * 6144;
    float*    XRING1 = (float*)(ws + XR1_OFF) + pair * 6144;
    uint32_t* HRING  = ws + HR0_OFF + pair * 1024;
    uint32_t* CTR    = ws + CTR_OFF;
    const int isbf   = (int)ws[FLG_OFF];

    uint32_t* myctr   = CTR + role * 1024 + pair * 16;
    uint32_t* prodctr = CTR + (role - 1) * 1024 + pair * 16;   // role>=1
    uint32_t* consctr = CTR + (role + 1) * 1024 + pair * 16;   // role<=2

    const void* Wsel; const void* bsel;
    if      (role == 0) { Wsel = Wx0; bsel = bx0; }
    else if (role == 1) { Wsel = Wh0; bsel = bh0; }
    else if (role == 2) { Wsel = Wx1; bsel = bx1; }
    else                { Wsel = Wh1; bsel = bh1; }

    // 12 named SSA weight vectors: half-rows of {p, p+256, p+512}
    u32x16 wr0,wr1,wr2,wr3, wz0,wz1,wz2,wz3, wn0,wn1,wn2,wn3;
    float br, bz, bn;
    if (isbf) {
        const uint4* W4 = (const uint4*)Wsel;
        const uint4* r0 = W4 + (size_t)p * 32 + hs * 16;
        const uint4* r1 = W4 + (size_t)(p + 256) * 32 + hs * 16;
        const uint4* r2 = W4 + (size_t)(p + 512) * 32 + hs * 16;
        wr0=load16_bf(r0);    wr1=load16_bf(r0+4);  wr2=load16_bf(r0+8);  wr3=load16_bf(r0+12);
        wz0=load16_bf(r1);    wz1=load16_bf(r1+4);  wz2=load16_bf(r1+8);  wz3=load16_bf(r1+12);
        wn0=load16_bf(r2);    wn1=load16_bf(r2+4);  wn2=load16_bf(r2+8);  wn3=load16_bf(r2+12);
        const uint16_t* bs = (const uint16_t*)bsel;
        br = bf2f(bs[p]); bz = bf2f(bs[p+256]); bn = bf2f(bs[p+512]);
    } else {
        const float2* W2 = (const float2*)Wsel;
        const float2* r0 = W2 + (size_t)p * 128 + hs * 64;
        const float2* r1 = W2 + (size_t)(p + 256) * 128 + hs * 64;
        const float2* r2 = W2 + (size_t)(p + 512) * 128 + hs * 64;
        wr0=load16_f32(r0);    wr1=load16_f32(r0+16); wr2=load16_f32(r0+32); wr3=load16_f32(r0+48);
        wz0=load16_f32(r1);    wz1=load16_f32(r1+16); wz2=load16_f32(r1+32); wz3=load16_f32(r1+48);
        wn0=load16_f32(r2);    wn1=load16_f32(r2+16); wn2=load16_f32(r2+32); wn3=load16_f32(r2+48);
        const float* bs = (const float*)bsel;
        br = bs[p]; bz = bs[p+256]; bn = bs[p+512];
    }

    // LDS: 2 buffers x 2 batches x (64 + skew4 + 64) dwords.
    // half hs=1 lives at +68 dwords => the wave's two broadcast rows hit
    // disjoint bank quads (no conflicts).  batch stride 136, buffer 272.
    __shared__ __align__(16) uint32_t sb[544];

    if (role == 0 || role == 2) {
        // ------------------------------ X stages ---------------------------
        const uint32_t* xs32 = (const uint32_t*)xin;
        const float2*   xsf  = (const float2*)xin;
        const int bglob = pair * 2 + (tid >> 7);
        const int i128  = tid & 127;
        const int spos  = (tid >> 7) * 136 + i128 + ((i128 >> 6) << 2);
        uint32_t xpref = 0, nxt = 0; bool have = false;
        if (role == 0 && tid < 256) {
            if (isbf) xpref = cvt_bfpair(xs32[(size_t)bglob * 131072 + i128]);
            else { float2 f = xsf[(size_t)bglob * 131072 + i128]; xpref = packpair(f.x, f.y); }
        }
        float* outring = (role == 0) ? XRING0 : XRING1;
        uint32_t prog_seen = 0;

        for (int t = 0; t < 1024; ++t) {
            if (t >= WSLOT && prog_seen + (WSLOT - 1) < (uint32_t)t) {
                do { prog_seen = RLX_LD(consctr);
                     if (prog_seen + (WSLOT - 1) < (uint32_t)t) __builtin_amdgcn_s_sleep(2);
                } while (prog_seen + (WSLOT - 1) < (uint32_t)t);
            }
            if (tid < 256) {
                uint32_t pk;
                if (role == 0) pk = xpref;
                else {
                    if (have) pk = nxt;
                    else {
                        uint32_t c;
                        do { c = RLX_LD(prodctr);
                             if (c < (uint32_t)(t + 1)) __builtin_amdgcn_s_sleep(2);
                        } while (c < (uint32_t)(t + 1));
                        pk = RLX_LD(HRING + (t & 3) * 256 + tid);
                    }
                }
                sb[(t & 1) * 272 + spos] = pk;
            }
            asm volatile("s_waitcnt vmcnt(0)" ::: "memory");  // ring stores(t-1) at MALL
            __syncthreads();
            if (tid == 0) RLX_ST(myctr, (uint32_t)t);          // certifies steps <= t-1
            if (tid < 256 && t < 1023) {                       // prefetch t+1
                if (role == 0) {
                    if (isbf) xpref = cvt_bfpair(xs32[(size_t)bglob * 131072 + (t+1)*128 + i128]);
                    else { float2 f = xsf[(size_t)bglob * 131072 + (t+1)*128 + i128]; xpref = packpair(f.x, f.y); }
                } else {
                    uint32_t c = RLX_LD(prodctr);
                    have = (c >= (uint32_t)(t + 2));
                    if (have) nxt = RLX_LD(HRING + ((t+1) & 3) * 256 + tid);
                }
            }
            float ar0=0,ar1=0,az0=0,az1=0,an0=0,an1=0;
            {
                const uint4* pa = ((const uint4*)&sb[(t & 1) * 272]) + hs * 17;
                const uint4* pb = pa + 34;
                DOT16(wr0,wz0,wn0,0); DOT16(wr1,wz1,wn1,1);
                DOT16(wr2,wz2,wn2,2); DOT16(wr3,wz3,wn3,3);
            }
            float R0 = ar0 + __shfl_xor(ar0,1), R1 = ar1 + __shfl_xor(ar1,1);
            float Z0 = az0 + __shfl_xor(az0,1), Z1 = az1 + __shfl_xor(az1,1);
            float N0 = an0 + __shfl_xor(an0,1), N1 = an1 + __shfl_xor(an1,1);
            float sr = (hs ? R1 : R0) + br;
            float sz = (hs ? Z1 : Z0) + bz;
            float sn = (hs ? N1 : N0) + bn;
            float* d = outring + (t & 3) * 1536;
            RLX_ST(d + 2*p + hs,        sr);
            RLX_ST(d + 512 + 2*p + hs,  sz);
            RLX_ST(d + 1024 + 2*p + hs, sn);
        }
        asm volatile("s_waitcnt vmcnt(0)" ::: "memory");
        __syncthreads();
        if (tid == 0) RLX_ST(myctr, 1024u);
    } else {
        // ------------------------------ H stages ---------------------------
        const float* xrng = (role == 1) ? XRING0 : XRING1;
        float h_reg = 0.0f;
        for (int i = tid; i < 544; i += 512) sb[i] = 0u;   // zero buf0 (+buf1)
        bool have = false; float nr=0, nz=0, nn=0;
        uint32_t prog_seen = 0;
        const int hj   = p >> 1;                            // h-pack dword idx
        const int hpos = hs * 136 + hj + ((hj >> 6) << 2);

        for (int t = 0; t < 1024; ++t) {
            if (role == 1 && t >= WSLOT && prog_seen + (WSLOT - 1) < (uint32_t)t) {
                do { prog_seen = RLX_LD(consctr);
                     if (prog_seen + (WSLOT - 1) < (uint32_t)t) __builtin_amdgcn_s_sleep(2);
                } while (prog_seen + (WSLOT - 1) < (uint32_t)t);
            }
            float xr, xz, xn;
            if (have) { xr = nr; xz = nz; xn = nn; }
            else {
                uint32_t c;
                do { c = RLX_LD(prodctr);
                     if (c < (uint32_t)(t + 1)) __builtin_amdgcn_s_sleep(2);
                } while (c < (uint32_t)(t + 1));
                const float* s = xrng + (t & 3) * 1536;
                xr = RLX_LD(s + 2*p + hs);
                xz = RLX_LD(s + 512 + 2*p + hs);
                xn = RLX_LD(s + 1024 + 2*p + hs);
            }
            asm volatile("s_waitcnt vmcnt(0)" ::: "memory");  // h-ring stores(t-1)
            __syncthreads();                                   // h(t) LDS writes visible
            if (tid == 0) RLX_ST(myctr, (uint32_t)t);
            if (t < 1023) {                                    // preload xt(t+1)
                uint32_t c = RLX_LD(prodctr);
                have = (c >= (uint32_t)(t + 2));
                if (have) {
                    const float* s = xrng + ((t + 1) & 3) * 1536;
                    nr = RLX_LD(s + 2*p + hs);
                    nz = RLX_LD(s + 512 + 2*p + hs);
                    nn = RLX_LD(s + 1024 + 2*p + hs);
                }
            } else have = false;
            float ar0=0,ar1=0,az0=0,az1=0,an0=0,an1=0;
            {
                const uint4* pa = ((const uint4*)&sb[(t & 1) * 272]) + hs * 17;
                const uint4* pb = pa + 34;
                DOT16(wr0,wz0,wn0,0); DOT16(wr1,wz1,wn1,1);
                DOT16(wr2,wz2,wn2,2); DOT16(wr3,wz3,wn3,3);
            }
            float R0 = ar0 + __shfl_xor(ar0,1), R1 = ar1 + __shfl_xor(ar1,1);
            float Z0 = az0 + __shfl_xor(az0,1), Z1 = az1 + __shfl_xor(az1,1);
            float N0 = an0 + __shfl_xor(an0,1), N1 = an1 + __shfl_xor(an1,1);
            float r = sigmoid_f(xr + (hs ? R1 : R0) + br);
            float z = sigmoid_f(xz + (hs ? Z1 : Z0) + bz);
            float n = tanh_f(xn + r * ((hs ? N1 : N0) + bn));
            h_reg = z * h_reg + (1.0f - z) * n;     // h[p], batch hs
            float hp = __shfl_xor(h_reg, 2);        // h[p^1], batch hs
            if (!(tid & 2)) {                       // p even: pack (h[p],h[p+1])
                uint32_t pk = packpair(h_reg, hp);
                sb[((t + 1) & 1) * 272 + hpos] = pk;
                if (role == 1)
                    RLX_ST(HRING + (t & 3) * 256 + hs * 128 + hj, pk);
            }
        }
        asm volatile("s_waitcnt vmcnt(0)" ::: "memory");
        __syncthreads();
        if (tid == 0) RLX_ST(myctr, 1024u);

        // ---------------- epilogue (role 3): out = h1.Wo^T + bo ------------
        if (role == 3 && tid < 256) {
            const int j = tid >> 1, bb = tid & 1;
            const uint32_t* hv = &sb[bb * 136];     // final h1 in buf0
            float acc;
            if (isbf) {
                acc = bf2f(((const uint16_t*)bo)[j]);
                const uint32_t* wo = (const uint32_t*)Wo + j * 128;
#pragma unroll 8
                for (int c = 0; c < 128; ++c)
                    acc = dot2acc(cvt_bfpair(wo[c]), hv[c + ((c >> 6) << 2)], acc);
                ((uint16_t*)out)[(pair * 2 + bb) * 128 + j] = f2bf(acc);
            } else {
                acc = ((const float*)bo)[j];
                const float2* wo = (const float2*)Wo + j * 128;
#pragma unroll 8
                for (int c = 0; c < 128; ++c) {
                    float2 f = wo[c];
                    acc = dot2acc(packpair(f.x, f.y), hv[c + ((c >> 6) << 2)], acc);
                }
                ((float*)out)[(pair * 2 + bb) * 128 + j] = acc;
            }
        }
    }
}

extern "C" void kernel_launch(void* const* d_in, const int* in_sizes, int n_in,
                              void* d_out, int out_size, void* d_ws, size_t ws_size,
                              hipStream_t stream) {
    uint32_t* ws  = (uint32_t*)d_ws;
    uint32_t* CTR = ws + CTR_OFF;
    uint32_t* FLG = ws + FLG_OFF;

    probe_init<<<dim3(1), dim3(1024), 0, stream>>>((const uint32_t*)d_in[1], CTR, FLG);
    gru6<<<dim3(256), dim3(512), 0, stream>>>(
        d_in[0], d_in[1], d_in[2], d_in[3], d_in[4],
        d_in[5], d_in[6], d_in[7], d_in[8], d_in[9], d_in[10],
        d_out, ws);
}

// Round 6
// 2710.733 us; speedup vs baseline: 22.6976x; 1.1188x over previous
//
#include <hip/hip_runtime.h>
#include <stdint.h>

// ---------------------------------------------------------------------------
// 2-layer GRU, B=128, T=1024, H=IN=256, OUT=128.  Dtype probed on device.
//
// v6: same 4-stage relaxed-sc1 spin-pipeline as v5 (256 blocks x 512 thr,
// roles L0X/L0H/L1X/L1H x 64 batch-pairs, weights register-resident, one
// barrier/step, skewed LDS).  Two changes:
//  1) amdgpu_waves_per_eu(2,2): unlock 256 arch VGPRs so all 192 weight
//     dwords sit in VGPRs (v5's VGPR_Count=128 meant half were in AGPRs,
//     +1 v_accvgpr_read per use -> VALU 2.5x the dot cost).
//  2) In-band tags: every ring payload is ONE 8-byte relaxed atomic
//     {payload, tag=t+1} (8B atomics are formally single-copy atomic).
//     X-ring entry = {f16 sr, f16 sz | f16 sn, tag16}; H-ring = {h-pair,
//     tag32}.  No flags, no vmcnt drains, no delayed certification ->
//     consumer prefetch for t+1 succeeds once the producer is ~1 step
//     ahead (the steady state), removing the per-step MALL round trip.
// ---------------------------------------------------------------------------

#define NPAIR 64

// ws layout in dwords
#define XR0_OFF 0            // uint2 [64][4][512]  (262144 dw)
#define XR1_OFF 262144       // uint2 [64][4][512]
#define HR0_OFF 524288       // uint2 [64][4][256]  (131072 dw)
#define CTR_OFF 655360       // u32   [4][64][16]
#define FLG_OFF 659456

#if defined(__has_builtin)
#if __has_builtin(__builtin_amdgcn_fdot2)
#define USE_DOT2 1
#endif
#endif

typedef uint32_t u32x16 __attribute__((ext_vector_type(16)));
typedef _Float16 h2_t __attribute__((ext_vector_type(2)));
union H2U { uint32_t u; h2_t h; };
union FU  { uint32_t u; float f; };

__device__ __forceinline__ float bf2f(uint16_t b){ FU v; v.u=(uint32_t)b<<16; return v.f; }
__device__ __forceinline__ uint16_t f2bf(float f){
    FU v; v.f=f; uint32_t r=v.u+0x7fffu+((v.u>>16)&1u); return (uint16_t)(r>>16);
}
__device__ __forceinline__ float sigmoid_f(float x){ return 1.0f/(1.0f+__expf(-x)); }
__device__ __forceinline__ float tanh_f(float x){
    float ax=fabsf(x); float e=__expf(-2.0f*ax);
    float t=(1.0f-e)/(1.0f+e); return x<0.0f?-t:t;
}
__device__ __forceinline__ float dot2acc(uint32_t w, uint32_t v, float acc){
#ifdef USE_DOT2
    H2U a,b; a.u=w; b.u=v;
    return __builtin_amdgcn_fdot2(a.h, b.h, acc, false);
#else
    FU x0,x1,y0,y1;
    x0.u=w<<16; x1.u=w&0xffff0000u; y0.u=v<<16; y1.u=v&0xffff0000u;
    acc=fmaf(x0.f,y0.f,acc); return fmaf(x1.f,y1.f,acc);
#endif
}
__device__ __forceinline__ uint32_t cvt_bfpair(uint32_t raw){
#ifdef USE_DOT2
    FU lo,hi; lo.u=raw<<16; hi.u=raw&0xffff0000u;
    H2U r; r.h[0]=(_Float16)lo.f; r.h[1]=(_Float16)hi.f; return r.u;
#else
    return raw;
#endif
}
__device__ __forceinline__ uint32_t packpair(float lo, float hi){
#ifdef USE_DOT2
    H2U r; r.h[0]=(_Float16)lo; r.h[1]=(_Float16)hi; return r.u;
#else
    return (uint32_t)f2bf(lo) | ((uint32_t)f2bf(hi)<<16);
#endif
}
__device__ __forceinline__ u32x16 load16_bf(const uint4* p){
    uint4 a=p[0], b=p[1], c=p[2], d=p[3];
    u32x16 v;
    v[0]=cvt_bfpair(a.x);  v[1]=cvt_bfpair(a.y);  v[2]=cvt_bfpair(a.z);  v[3]=cvt_bfpair(a.w);
    v[4]=cvt_bfpair(b.x);  v[5]=cvt_bfpair(b.y);  v[6]=cvt_bfpair(b.z);  v[7]=cvt_bfpair(b.w);
    v[8]=cvt_bfpair(c.x);  v[9]=cvt_bfpair(c.y);  v[10]=cvt_bfpair(c.z); v[11]=cvt_bfpair(c.w);
    v[12]=cvt_bfpair(d.x); v[13]=cvt_bfpair(d.y); v[14]=cvt_bfpair(d.z); v[15]=cvt_bfpair(d.w);
    return v;
}
__device__ __forceinline__ u32x16 load16_f32(const float2* p){
    u32x16 v;
#define LF(i) v[i] = packpair(p[i].x, p[i].y)
    LF(0);LF(1);LF(2);LF(3);LF(4);LF(5);LF(6);LF(7);
    LF(8);LF(9);LF(10);LF(11);LF(12);LF(13);LF(14);LF(15);
#undef LF
    return v;
}

#define RLX_LD(p)    __hip_atomic_load((p),        __ATOMIC_RELAXED, __HIP_MEMORY_SCOPE_AGENT)
#define RLX_ST(p,v)  __hip_atomic_store((p), (v),  __ATOMIC_RELAXED, __HIP_MEMORY_SCOPE_AGENT)
__device__ __forceinline__ uint64_t RLX_LD64(const uint64_t* p){
    return __hip_atomic_load(p, __ATOMIC_RELAXED, __HIP_MEMORY_SCOPE_AGENT);
}
__device__ __forceinline__ void RLX_ST64(uint64_t* p, uint64_t v){
    __hip_atomic_store(p, v, __ATOMIC_RELAXED, __HIP_MEMORY_SCOPE_AGENT);
}

// 16 dwords of input (one quarter of this lane's half) vs 3 weight vecs
#define DOT16(WR, WZ, WN, G)                                                      \
    _Pragma("unroll")                                                             \
    for (int q = 0; q < 4; ++q) {                                                 \
        uint4 va = pa[4*(G)+q], vb = pb[4*(G)+q];                                 \
        ar0 = dot2acc(WR[4*q+0], va.x, ar0); ar1 = dot2acc(WR[4*q+0], vb.x, ar1); \
        az0 = dot2acc(WZ[4*q+0], va.x, az0); az1 = dot2acc(WZ[4*q+0], vb.x, az1); \
        an0 = dot2acc(WN[4*q+0], va.x, an0); an1 = dot2acc(WN[4*q+0], vb.x, an1); \
        ar0 = dot2acc(WR[4*q+1], va.y, ar0); ar1 = dot2acc(WR[4*q+1], vb.y, ar1); \
        az0 = dot2acc(WZ[4*q+1], va.y, az0); az1 = dot2acc(WZ[4*q+1], vb.y, az1); \
        an0 = dot2acc(WN[4*q+1], va.y, an0); an1 = dot2acc(WN[4*q+1], vb.y, an1); \
        ar0 = dot2acc(WR[4*q+2], va.z, ar0); ar1 = dot2acc(WR[4*q+2], vb.z, ar1); \
        az0 = dot2acc(WZ[4*q+2], va.z, az0); az1 = dot2acc(WZ[4*q+2], vb.z, az1); \
        an0 = dot2acc(WN[4*q+2], va.z, an0); an1 = dot2acc(WN[4*q+2], vb.z, an1); \
        ar0 = dot2acc(WR[4*q+3], va.w, ar0); ar1 = dot2acc(WR[4*q+3], vb.w, ar1); \
        az0 = dot2acc(WZ[4*q+3], va.w, az0); az1 = dot2acc(WZ[4*q+3], vb.w, az1); \
        an0 = dot2acc(WN[4*q+3], va.w, an0); an1 = dot2acc(WN[4*q+3], vb.w, an1); \
    }

__global__ void probe_init(const uint32_t* __restrict__ w,
                           uint32_t* __restrict__ ctr,
                           uint32_t* __restrict__ flag) {
    int i = threadIdx.x;
    for (int k = i; k < 4096; k += 1024) ctr[k] = 0u;
    if (i == 0) {
        int c = 0;
        for (int j = 0; j < 64; ++j) {
            uint32_t e = (w[j] >> 7) & 0xFFu;
            c += (e >= 0x60u && e <= 0x7Cu) ? 1 : 0;
        }
        flag[0] = (c >= 32) ? 1u : 0u;
    }
}

__global__ void __launch_bounds__(512) __attribute__((amdgpu_waves_per_eu(2, 2)))
gru7(const void* __restrict__ xin,
     const void* __restrict__ Wx0, const void* __restrict__ bx0,
     const void* __restrict__ Wh0, const void* __restrict__ bh0,
     const void* __restrict__ Wx1, const void* __restrict__ bx1,
     const void* __restrict__ Wh1, const void* __restrict__ bh1,
     const void* __restrict__ Wo,  const void* __restrict__ bo,
     void* __restrict__ out,
     uint32_t* __restrict__ ws)
{
    const int tid  = threadIdx.x;
    const int pair = blockIdx.x & (NPAIR - 1);
    const int role = blockIdx.x >> 6;
    const int p    = tid >> 1;       // hidden unit / row base
    const int hs   = tid & 1;        // column half (X) / batch index (H)

    uint64_t* XR0p = (uint64_t*)(ws + XR0_OFF) + pair * 2048;   // 4 slots x 512
    uint64_t* XR1p = (uint64_t*)(ws + XR1_OFF) + pair * 2048;
    uint64_t* HRp  = (uint64_t*)(ws + HR0_OFF) + pair * 1024;   // 4 slots x 256
    uint32_t* CTR  = ws + CTR_OFF;
    const int isbf = (int)ws[FLG_OFF];

    uint32_t* myprg   = CTR + role * 1024 + pair * 16;          // my staged step
    uint32_t* consprg = CTR + (role + 1) * 1024 + pair * 16;    // downstream's

    const void* Wsel; const void* bsel;
    if      (role == 0) { Wsel = Wx0; bsel = bx0; }
    else if (role == 1) { Wsel = Wh0; bsel = bh0; }
    else if (role == 2) { Wsel = Wx1; bsel = bx1; }
    else                { Wsel = Wh1; bsel = bh1; }

    // 12 named SSA weight vectors: half-rows of {p, p+256, p+512}
    u32x16 wr0,wr1,wr2,wr3, wz0,wz1,wz2,wz3, wn0,wn1,wn2,wn3;
    float br, bz, bn;
    if (isbf) {
        const uint4* W4 = (const uint4*)Wsel;
        const uint4* r0 = W4 + (size_t)p * 32 + hs * 16;
        const uint4* r1 = W4 + (size_t)(p + 256) * 32 + hs * 16;
        const uint4* r2 = W4 + (size_t)(p + 512) * 32 + hs * 16;
        wr0=load16_bf(r0);    wr1=load16_bf(r0+4);  wr2=load16_bf(r0+8);  wr3=load16_bf(r0+12);
        wz0=load16_bf(r1);    wz1=load16_bf(r1+4);  wz2=load16_bf(r1+8);  wz3=load16_bf(r1+12);
        wn0=load16_bf(r2);    wn1=load16_bf(r2+4);  wn2=load16_bf(r2+8);  wn3=load16_bf(r2+12);
        const uint16_t* bs = (const uint16_t*)bsel;
        br = bf2f(bs[p]); bz = bf2f(bs[p+256]); bn = bf2f(bs[p+512]);
    } else {
        const float2* W2 = (const float2*)Wsel;
        const float2* r0 = W2 + (size_t)p * 128 + hs * 64;
        const float2* r1 = W2 + (size_t)(p + 256) * 128 + hs * 64;
        const float2* r2 = W2 + (size_t)(p + 512) * 128 + hs * 64;
        wr0=load16_f32(r0);    wr1=load16_f32(r0+16); wr2=load16_f32(r0+32); wr3=load16_f32(r0+48);
        wz0=load16_f32(r1);    wz1=load16_f32(r1+16); wz2=load16_f32(r1+32); wz3=load16_f32(r1+48);
        wn0=load16_f32(r2);    wn1=load16_f32(r2+16); wn2=load16_f32(r2+32); wn3=load16_f32(r2+48);
        const float* bs = (const float*)bsel;
        br = bs[p]; bz = bs[p+256]; bn = bs[p+512];
    }

    // skewed LDS: 2 buffers x (2 x 136-dw halves); hs=1 half at +68 dwords
    __shared__ __align__(16) uint32_t sb[544];

    if (role == 0 || role == 2) {
        // ------------------------------ X stages ---------------------------
        const uint32_t* xs32 = (const uint32_t*)xin;
        const float2*   xsf  = (const float2*)xin;
        const int bglob = pair * 2 + (tid >> 7);
        const int i128  = tid & 127;
        const int spos  = (tid >> 7) * 136 + i128 + ((i128 >> 6) << 2);
        uint32_t xpref = 0;
        uint2 pfh; pfh.x = 0; pfh.y = 0;
        if (role == 0 && tid < 256) {
            if (isbf) xpref = cvt_bfpair(xs32[(size_t)bglob * 131072 + i128]);
            else { float2 f = xsf[(size_t)bglob * 131072 + i128]; xpref = packpair(f.x, f.y); }
        }
        uint64_t* outring = (role == 0) ? XR0p : XR1p;
        uint32_t prog_seen = 0;

        for (int t = 0; t < 1024; ++t) {
            if (t >= 4 && prog_seen + 3 < (uint32_t)t) {     // ring-wrap guard
                do { prog_seen = RLX_LD(consprg);
                     if (prog_seen + 3 < (uint32_t)t) __builtin_amdgcn_s_sleep(2);
                } while (prog_seen + 3 < (uint32_t)t);
            }
            if (tid < 256) {
                uint32_t pk;
                if (role == 0) pk = xpref;
                else {
                    uint2 v = pfh;
                    const uint32_t want = (uint32_t)(t + 1);
                    if (v.y != want) {
                        const uint64_t* a = HRp + (t & 3) * 256 + tid;
                        uint64_t u;
                        do { u = RLX_LD64(a);
                             v.x = (uint32_t)u; v.y = (uint32_t)(u >> 32);
                             if (v.y != want) __builtin_amdgcn_s_sleep(1);
                        } while (v.y != want);
                    }
                    pk = v.x;
                }
                sb[(t & 1) * 272 + spos] = pk;
            }
            __syncthreads();
            if (tid == 0 && !(t & 1)) RLX_ST(myprg, (uint32_t)t);
            if (tid < 256 && t < 1023) {                     // prefetch t+1
                if (role == 0) {
                    if (isbf) xpref = cvt_bfpair(xs32[(size_t)bglob * 131072 + (t+1)*128 + i128]);
                    else { float2 f = xsf[(size_t)bglob * 131072 + (t+1)*128 + i128]; xpref = packpair(f.x, f.y); }
                } else {
                    uint64_t u = RLX_LD64(HRp + ((t + 1) & 3) * 256 + tid);
                    pfh.x = (uint32_t)u; pfh.y = (uint32_t)(u >> 32);
                }
            }
            float ar0=0,ar1=0,az0=0,az1=0,an0=0,an1=0;
            {
                const uint4* pa = ((const uint4*)&sb[(t & 1) * 272]) + hs * 17;
                const uint4* pb = pa + 34;
                DOT16(wr0,wz0,wn0,0); DOT16(wr1,wz1,wn1,1);
                DOT16(wr2,wz2,wn2,2); DOT16(wr3,wz3,wn3,3);
            }
            float R0 = ar0 + __shfl_xor(ar0,1), R1 = ar1 + __shfl_xor(ar1,1);
            float Z0 = az0 + __shfl_xor(az0,1), Z1 = az1 + __shfl_xor(az1,1);
            float N0 = an0 + __shfl_xor(an0,1), N1 = an1 + __shfl_xor(an1,1);
            float sr = (hs ? R1 : R0) + br;
            float sz = (hs ? Z1 : Z0) + bz;
            float sn = (hs ? N1 : N0) + bn;
            // publish {f16 sr, f16 sz | f16 sn, tag16} as one 8B atomic
            H2U lo; lo.h[0] = (_Float16)sr; lo.h[1] = (_Float16)sz;
            H2U sn16; sn16.u = 0; sn16.h[0] = (_Float16)sn;
            uint32_t hi = (sn16.u & 0xFFFFu) | (((uint32_t)(t + 1)) << 16);
            RLX_ST64(outring + (t & 3) * 512 + 2 * p + hs,
                     (uint64_t)lo.u | ((uint64_t)hi << 32));
        }
    } else {
        // ------------------------------ H stages ---------------------------
        const uint64_t* xr64 = (role == 1) ? XR0p : XR1p;
        float h_reg = 0.0f;
        for (int i = tid; i < 544; i += 512) sb[i] = 0u;   // h(0) = 0
        uint2 pfx; pfx.x = 0; pfx.y = 0;
        uint32_t prog_seen = 0;
        const int hj   = p >> 1;
        const int hpos = hs * 136 + hj + ((hj >> 6) << 2);

        for (int t = 0; t < 1024; ++t) {
            if (role == 1 && t >= 4 && prog_seen + 3 < (uint32_t)t) {
                do { prog_seen = RLX_LD(consprg);
                     if (prog_seen + 3 < (uint32_t)t) __builtin_amdgcn_s_sleep(2);
                } while (prog_seen + 3 < (uint32_t)t);
            }
            uint2 v = pfx;
            const uint32_t want = (uint32_t)(t + 1);
            if ((v.y >> 16) != want) {
                const uint64_t* a = xr64 + (t & 3) * 512 + 2 * p + hs;
                uint64_t u;
                do { u = RLX_LD64(a);
                     v.x = (uint32_t)u; v.y = (uint32_t)(u >> 32);
                     if ((v.y >> 16) != want) __builtin_amdgcn_s_sleep(1);
                } while ((v.y >> 16) != want);
            }
            H2U ua; ua.u = v.x;
            H2U ub; ub.u = v.y & 0xFFFFu;
            float xr = (float)ua.h[0], xz = (float)ua.h[1], xn = (float)ub.h[0];
            __syncthreads();                 // h(t) LDS writes (prev iter) visible
            if (tid == 0 && !(t & 1)) RLX_ST(myprg, (uint32_t)t);
            if (t < 1023) {                  // prefetch t+1
                uint64_t u = RLX_LD64(xr64 + ((t + 1) & 3) * 512 + 2 * p + hs);
                pfx.x = (uint32_t)u; pfx.y = (uint32_t)(u >> 32);
            }
            float ar0=0,ar1=0,az0=0,az1=0,an0=0,an1=0;
            {
                const uint4* pa = ((const uint4*)&sb[(t & 1) * 272]) + hs * 17;
                const uint4* pb = pa + 34;
                DOT16(wr0,wz0,wn0,0); DOT16(wr1,wz1,wn1,1);
                DOT16(wr2,wz2,wn2,2); DOT16(wr3,wz3,wn3,3);
            }
            float R0 = ar0 + __shfl_xor(ar0,1), R1 = ar1 + __shfl_xor(ar1,1);
            float Z0 = az0 + __shfl_xor(az0,1), Z1 = az1 + __shfl_xor(az1,1);
            float N0 = an0 + __shfl_xor(an0,1), N1 = an1 + __shfl_xor(an1,1);
            float r = sigmoid_f(xr + (hs ? R1 : R0) + br);
            float z = sigmoid_f(xz + (hs ? Z1 : Z0) + bz);
            float n = tanh_f(xn + r * ((hs ? N1 : N0) + bn));
            h_reg = z * h_reg + (1.0f - z) * n;     // h[p], batch hs
            float hp = __shfl_xor(h_reg, 2);        // h[p^1], batch hs
            if (!(tid & 2)) {                       // p even: pack (h[p],h[p+1])
                uint32_t pk = packpair(h_reg, hp);
                sb[((t + 1) & 1) * 272 + hpos] = pk;
                if (role == 1)
                    RLX_ST64(HRp + (t & 3) * 256 + hs * 128 + hj,
                             (uint64_t)pk | ((uint64_t)(t + 1) << 32));
            }
        }
        __syncthreads();
        if (tid == 0) RLX_ST(myprg, 1024u);

        // ---------------- epilogue (role 3): out = h1.Wo^T + bo ------------
        if (role == 3 && tid < 256) {
            const int j = tid >> 1, bb = tid & 1;
            const uint32_t* hv = &sb[bb * 136];     // final h1 in buffer 0
            float acc;
            if (isbf) {
                acc = bf2f(((const uint16_t*)bo)[j]);
                const uint32_t* wo = (const uint32_t*)Wo + j * 128;
#pragma unroll 8
                for (int c = 0; c < 128; ++c)
                    acc = dot2acc(cvt_bfpair(wo[c]), hv[c + ((c >> 6) << 2)], acc);
                ((uint16_t*)out)[(pair * 2 + bb) * 128 + j] = f2bf(acc);
            } else {
                acc = ((const float*)bo)[j];
                const float2* wo = (const float2*)Wo + j * 128;
#pragma unroll 8
                for (int c = 0; c < 128; ++c) {
                    float2 f = wo[c];
                    acc = dot2acc(packpair(f.x, f.y), hv[c + ((c >> 6) << 2)], acc);
                }
                ((float*)out)[(pair * 2 + bb) * 128 + j] = acc;
            }
        }
    }
}

extern "C" void kernel_launch(void* const* d_in, const int* in_sizes, int n_in,
                              void* d_out, int out_size, void* d_ws, size_t ws_size,
                              hipStream_t stream) {
    uint32_t* ws  = (uint32_t*)d_ws;
    uint32_t* CTR = ws + CTR_OFF;
    uint32_t* FLG = ws + FLG_OFF;

    probe_init<<<dim3(1), dim3(1024), 0, stream>>>((const uint32_t*)d_in[1], CTR, FLG);
    gru7<<<dim3(256), dim3(512), 0, stream>>>(
        d_in[0], d_in[1], d_in[2], d_in[3], d_in[4],
        d_in[5], d_in[6], d_in[7], d_in[8], d_in[9], d_in[10],
        d_out, ws);
}